// Round 7
// baseline (425.295 us; speedup 1.0000x reference)
//
#include <hip/hip_runtime.h>
#include <math.h>
#include <limits.h>

#define M_ROWS 65536   // B*N = 64*1024
#define DD     256     // feature dim
#define KC     512     // codes
#define RPW    16      // rows per wave (z via scalar pipe -> rows are cheap)
#define WAVES  8
#define RPB    (RPW * WAVES)   // 128 rows per block
#define KS     32      // k-slice floats (8 float4 columns); 8 slices

// numpy-style pairwise sum (8 accumulators, block 128) of squares of 128 floats.
__device__ __forceinline__ float pw128_sq(const float4* __restrict__ q) {
  float r[8];
  {
    float4 a = q[0], b = q[1];
    r[0] = __fmul_rn(a.x, a.x); r[1] = __fmul_rn(a.y, a.y);
    r[2] = __fmul_rn(a.z, a.z); r[3] = __fmul_rn(a.w, a.w);
    r[4] = __fmul_rn(b.x, b.x); r[5] = __fmul_rn(b.y, b.y);
    r[6] = __fmul_rn(b.z, b.z); r[7] = __fmul_rn(b.w, b.w);
  }
#pragma unroll
  for (int i = 2; i < 32; i += 2) {
    float4 a = q[i], b = q[i + 1];
    r[0] = __fadd_rn(r[0], __fmul_rn(a.x, a.x));
    r[1] = __fadd_rn(r[1], __fmul_rn(a.y, a.y));
    r[2] = __fadd_rn(r[2], __fmul_rn(a.z, a.z));
    r[3] = __fadd_rn(r[3], __fmul_rn(a.w, a.w));
    r[4] = __fadd_rn(r[4], __fmul_rn(b.x, b.x));
    r[5] = __fadd_rn(r[5], __fmul_rn(b.y, b.y));
    r[6] = __fadd_rn(r[6], __fmul_rn(b.z, b.z));
    r[7] = __fadd_rn(r[7], __fmul_rn(b.w, b.w));
  }
  return __fadd_rn(__fadd_rn(__fadd_rn(r[0], r[1]), __fadd_rn(r[2], r[3])),
                   __fadd_rn(__fadd_rn(r[4], r[5]), __fadd_rn(r[6], r[7])));
}

__global__ void sumsq_kernel(const float* __restrict__ x, float* __restrict__ s,
                             int nrows) {
  int r = blockIdx.x * blockDim.x + threadIdx.x;
  if (r >= nrows) return;
  const float4* q = (const float4*)(x + (size_t)r * DD);
  s[r] = __fadd_rn(pw128_sq(q), pw128_sq(q + 32));
}

// async global->LDS, 16B/lane: LDS dest = wave-uniform base + lane*16
typedef __attribute__((address_space(1))) const void gas_void;
typedef __attribute__((address_space(3))) void las_void;
__device__ __forceinline__ void gl_lds16(const void* g, void* l) {
  __builtin_amdgcn_global_load_lds((gas_void*)g, (las_void*)l, 16, 0, 0);
}

// 8-wave block, 16 rows/wave, all 512 codes per block.
//  - z: wave-uniform rows -> scalar (SMEM) pipe, zero LDS / VALU cost
//  - e: k-slices (32 floats) of all 512 codes, double-buffered 2x64 KB LDS,
//    staged via global_load_lds with prefetch one slice ahead (stage issued
//    BEFORE compute; the vmcnt(0) drain at the barrier lands ~16k cyc later).
//  - LDS layout: code c, float4-col q at slot c*8 + (q ^ (c&7)): the 64-lane
//    column read (c=lane, fixed q) touches 8 bank-groups x 8 lanes = all 32
//    banks each phase -> conflict-free b128 floor.
__global__ __launch_bounds__(512) void vq_kernel(
    const float* __restrict__ z, const float* __restrict__ cb,
    const float* __restrict__ s, const float* __restrict__ se,
    float* __restrict__ out) {
  __shared__ float4 es4[2][KC * 8];   // 2 x 64 KB
  __shared__ int best_l[RPB];

  const int tid = threadIdx.x;
  const int lane = tid & 63;
  const int wv = tid >> 6;                    // wave 0..7
  const int rowbase =
      __builtin_amdgcn_readfirstlane((int)blockIdx.x * RPB + wv * RPW);
  const float4* zq = (const float4*)(z + (size_t)rowbase * DD);  // uniform
  const float4* cg = (const float4*)cb;
  const int esw = lane & 7;                   // read-side swizzle

  // ||e||^2 for this lane's 8 codes (c = lane + 64j)
  float se_reg[8];
#pragma unroll
  for (int j = 0; j < 8; ++j) se_reg[j] = se[lane + 64 * j];

  float acc[RPW][8];
#pragma unroll
  for (int i = 0; i < RPW; ++i)
#pragma unroll
    for (int j = 0; j < 8; ++j) acc[i][j] = 0.0f;

  // stage one 64 KB slice (all codes, 8 f4 cols) into buffer b:
  // 4096 slots; 8 rounds x 512 threads; linear LDS dest, inverse-swizzled src
  auto stage = [&](int b, int ks) {
#pragma unroll
    for (int seg = 0; seg < 8; ++seg) {
      int u = seg * 512 + tid;                // linear slot
      int c = u >> 3, qs = u & 7;
      int q = qs ^ (c & 7);
      gl_lds16(&cg[(size_t)c * 64 + ks * 8 + q],
               (char*)&es4[b][0] + (size_t)(seg * 512 + wv * 64) * 16);
    }
  };

  auto compute = [&](int b, int ks) {
#pragma unroll
    for (int k4 = 0; k4 < 8; ++k4) {
      const float4* ep = &es4[b][lane * 8 + (k4 ^ esw)];
      float4 ef[8];
#pragma unroll
      for (int j = 0; j < 8; ++j) ef[j] = ep[j * 512];  // code lane+64j
#pragma unroll
      for (int i = 0; i < RPW; ++i) {
        float4 zf = zq[(size_t)i * 64 + ks * 8 + k4];   // scalar (uniform)
#pragma unroll
        for (int j = 0; j < 8; ++j) {
          // strict k-ascending FMA chain per (row, code) — bit-identical
          acc[i][j] = __fmaf_rn(zf.x, ef[j].x, acc[i][j]);
          acc[i][j] = __fmaf_rn(zf.y, ef[j].y, acc[i][j]);
          acc[i][j] = __fmaf_rn(zf.z, ef[j].z, acc[i][j]);
          acc[i][j] = __fmaf_rn(zf.w, ef[j].w, acc[i][j]);
        }
      }
    }
  };

  stage(0, 0);
  __syncthreads();                 // prologue drain
  int b = 0;
#pragma unroll 1
  for (int ks = 0; ks < DD / KS; ++ks) {      // 8 slices
    if (ks < DD / KS - 1) stage(b ^ 1, ks + 1);   // prefetch next (hidden)
    compute(b, ks);
    __syncthreads();               // single barrier/slice
    b ^= 1;
  }

  // d = (s - 2*dot) + se, rounded exactly like the reference; lexicographic
  // (d, code) argmin -> first-index tie-break preserved
#pragma unroll
  for (int i = 0; i < RPW; ++i) {
    float s_r = s[rowbase + i];               // wave-uniform scalar load
    float bd = INFINITY;
    int   bi = INT_MAX;
#pragma unroll
    for (int j = 0; j < 8; ++j) {
      int code = lane + 64 * j;
      float d = __fadd_rn(__fsub_rn(s_r, __fmul_rn(2.0f, acc[i][j])),
                          se_reg[j]);
      if (d < bd || (d == bd && code < bi)) { bd = d; bi = code; }
    }
#pragma unroll
    for (int off = 1; off < 64; off <<= 1) {  // full-wave reduce
      float od = __shfl_xor(bd, off, 64);
      int   oi = __shfl_xor(bi, off, 64);
      if (od < bd || (od == bd && oi < bi)) { bd = od; bi = oi; }
    }
    if (lane == 0) best_l[wv * RPW + i] = bi;
  }
  __syncthreads();

  // epilogue: out0 = fl(z + fl(cb[idx]-z)), out1 = cb[idx]  (128 rows/block)
  const int r0 = blockIdx.x * RPB;
  const float4* zg = (const float4*)z;
  float4* out0 = (float4*)out;
  float4* out1 = (float4*)(out + (size_t)M_ROWS * DD);
#pragma unroll
  for (int it = 0; it < (RPB * 64) / 512; ++it) {
    int u = it * 512 + tid;
    int row = u >> 6, c4 = u & 63;
    size_t gidx = (size_t)(r0 + row) * 64 + c4;
    float4 zv = zg[gidx];
    float4 cv = cg[(size_t)best_l[row] * 64 + c4];
    float4 o0;
    o0.x = __fadd_rn(zv.x, __fsub_rn(cv.x, zv.x));
    o0.y = __fadd_rn(zv.y, __fsub_rn(cv.y, zv.y));
    o0.z = __fadd_rn(zv.z, __fsub_rn(cv.z, zv.z));
    o0.w = __fadd_rn(zv.w, __fsub_rn(cv.w, zv.w));
    out0[gidx] = o0;
    out1[gidx] = cv;
  }
}

extern "C" void kernel_launch(void* const* d_in, const int* in_sizes, int n_in,
                              void* d_out, int out_size, void* d_ws, size_t ws_size,
                              hipStream_t stream) {
  const float* z  = (const float*)d_in[0];   // [65536, 256]
  const float* cb = (const float*)d_in[1];   // [512, 256]
  float* out = (float*)d_out;                // 2 x [65536, 256] concat
  float* s  = (float*)d_ws;                  // ||z||^2 per row
  float* se = s + M_ROWS;                    // ||e||^2 per code

  sumsq_kernel<<<M_ROWS / 256, 256, 0, stream>>>(z, s, M_ROWS);
  sumsq_kernel<<<KC / 256, 256, 0, stream>>>(cb, se, KC);
  vq_kernel<<<M_ROWS / RPB, 512, 0, stream>>>(z, cb, s, se, out);
}

// Round 8
// 315.242 us; speedup vs baseline: 1.3491x; 1.3491x over previous
//
#include <hip/hip_runtime.h>
#include <math.h>
#include <limits.h>

#define M_ROWS 65536   // B*N = 64*1024
#define DD     256     // feature dim
#define KC     512     // codes
#define RPW    8       // rows per wave (z via scalar pipe)
#define WAVES  4
#define RPB    (RPW * WAVES)    // 32 rows per block
#define CHUNK  128              // codes per chunk (4 chunks)
#define KS     32               // k-slice floats = 8 float4 cols
#define ROUNDS 32               // 4 chunks x 8 slices

// numpy-style pairwise sum (8 accumulators, block 128) of squares of 128 floats.
__device__ __forceinline__ float pw128_sq(const float4* __restrict__ q) {
  float r[8];
  {
    float4 a = q[0], b = q[1];
    r[0] = __fmul_rn(a.x, a.x); r[1] = __fmul_rn(a.y, a.y);
    r[2] = __fmul_rn(a.z, a.z); r[3] = __fmul_rn(a.w, a.w);
    r[4] = __fmul_rn(b.x, b.x); r[5] = __fmul_rn(b.y, b.y);
    r[6] = __fmul_rn(b.z, b.z); r[7] = __fmul_rn(b.w, b.w);
  }
#pragma unroll
  for (int i = 2; i < 32; i += 2) {
    float4 a = q[i], b = q[i + 1];
    r[0] = __fadd_rn(r[0], __fmul_rn(a.x, a.x));
    r[1] = __fadd_rn(r[1], __fmul_rn(a.y, a.y));
    r[2] = __fadd_rn(r[2], __fmul_rn(a.z, a.z));
    r[3] = __fadd_rn(r[3], __fmul_rn(a.w, a.w));
    r[4] = __fadd_rn(r[4], __fmul_rn(b.x, b.x));
    r[5] = __fadd_rn(r[5], __fmul_rn(b.y, b.y));
    r[6] = __fadd_rn(r[6], __fmul_rn(b.z, b.z));
    r[7] = __fadd_rn(r[7], __fmul_rn(b.w, b.w));
  }
  return __fadd_rn(__fadd_rn(__fadd_rn(r[0], r[1]), __fadd_rn(r[2], r[3])),
                   __fadd_rn(__fadd_rn(r[4], r[5]), __fadd_rn(r[6], r[7])));
}

__global__ void sumsq_kernel(const float* __restrict__ x, float* __restrict__ s,
                             int nrows) {
  int r = blockIdx.x * blockDim.x + threadIdx.x;
  if (r >= nrows) return;
  const float4* q = (const float4*)(x + (size_t)r * DD);
  s[r] = __fadd_rn(pw128_sq(q), pw128_sq(q + 32));
}

// async global->LDS, 16B/lane: LDS dest = wave-uniform base + lane*16
typedef __attribute__((address_space(1))) const void gas_void;
typedef __attribute__((address_space(3))) void las_void;
__device__ __forceinline__ void gl_lds16(const void* g, void* l) {
  __builtin_amdgcn_global_load_lds((gas_void*)g, (las_void*)l, 16, 0, 0);
}

// Structure (round 8):
//  - z: wave-uniform rows -> scalar (SMEM) pipe; 8 rows/wave.
//  - e: 128-code chunks, k-slices of 32 floats, DOUBLE-BUFFERED 2x16 KB LDS,
//    prefetch issued before compute; one barrier per round. 4 blocks/CU.
//  - LDS row = 8 float4, slot = c*8 + (q ^ (c&7)) (r7's lower-conflict
//    swizzle); linear LDS dest + inverse-swizzled global source.
//  - acc[8][2] (lane owns 2 codes/chunk) -> ~55 VGPR, no spill.
__global__ __launch_bounds__(256, 4) void vq_kernel(
    const float* __restrict__ z, const float* __restrict__ cb,
    const float* __restrict__ s, const float* __restrict__ se,
    float* __restrict__ out) {
  __shared__ float4 es4[2][CHUNK * 8];   // 2 x 16 KB
  __shared__ int best_l[RPB];

  const int tid = threadIdx.x;
  const int lane = tid & 63;
  const int wv = tid >> 6;                    // wave 0..3
  const int rowbase =
      __builtin_amdgcn_readfirstlane((int)blockIdx.x * RPB + wv * RPW);
  const float4* zq = (const float4*)(z + (size_t)rowbase * DD);  // uniform
  const float4* cg = (const float4*)cb;
  const int esw = lane & 7;                   // read-side swizzle

  // ||z||^2 for the wave's 8 rows (wave-uniform -> SGPRs)
  float s_reg[RPW];
#pragma unroll
  for (int i = 0; i < RPW; ++i) s_reg[i] = s[rowbase + i];

  float bestd[RPW];
  int   besti[RPW];
#pragma unroll
  for (int i = 0; i < RPW; ++i) { bestd[i] = INFINITY; besti[i] = INT_MAX; }

  float acc[RPW][2];
  float se_reg[2];

  // stage chunk/slice of round r into buffer b: 128 codes x 8 f4 = 1024 slots,
  // 4 segs x 256 threads; linear LDS dest, inverse-swizzled global source.
  auto stage = [&](int b, int r) {
    const int cbase = (r >> 3) * CHUNK;
    const int ks = r & 7;
#pragma unroll
    for (int seg = 0; seg < 4; ++seg) {
      int u = seg * 256 + tid;                // linear slot
      int c = u >> 3, qs = u & 7;
      int q = qs ^ (c & 7);
      gl_lds16(&cg[(size_t)(cbase + c) * 64 + ks * 8 + q],
               (char*)&es4[b][0] + (seg * 256 + wv * 64) * 16);
    }
  };

  stage(0, 0);
  __syncthreads();                            // prologue drain
  int b = 0;

#pragma unroll 1
  for (int r = 0; r < ROUNDS; ++r) {
    const int ks = r & 7;
    const int ch = r >> 3;
    if (ks == 0) {                            // chunk entry: se + acc reset
      se_reg[0] = se[ch * CHUNK + lane];
      se_reg[1] = se[ch * CHUNK + 64 + lane];
#pragma unroll
      for (int i = 0; i < RPW; ++i) { acc[i][0] = 0.0f; acc[i][1] = 0.0f; }
    }
    if (r < ROUNDS - 1) stage(b ^ 1, r + 1);  // prefetch (lands under compute)

    // compute slice ks of current chunk from buffer b
#pragma unroll
    for (int k4 = 0; k4 < 8; ++k4) {
      const float4* ep = &es4[b][lane * 8 + (k4 ^ esw)];
      float4 ef0 = ep[0];                     // code lane
      float4 ef1 = ep[512];                   // code lane+64 (offset 8192 B)
#pragma unroll
      for (int i = 0; i < RPW; ++i) {
        float4 zf = zq[(size_t)i * 64 + ks * 8 + k4];   // scalar (uniform)
        // strict k-ascending FMA chain per (row, code) — bit-identical to ref
        acc[i][0] = __fmaf_rn(zf.x, ef0.x, acc[i][0]);
        acc[i][0] = __fmaf_rn(zf.y, ef0.y, acc[i][0]);
        acc[i][0] = __fmaf_rn(zf.z, ef0.z, acc[i][0]);
        acc[i][0] = __fmaf_rn(zf.w, ef0.w, acc[i][0]);
        acc[i][1] = __fmaf_rn(zf.x, ef1.x, acc[i][1]);
        acc[i][1] = __fmaf_rn(zf.y, ef1.y, acc[i][1]);
        acc[i][1] = __fmaf_rn(zf.z, ef1.z, acc[i][1]);
        acc[i][1] = __fmaf_rn(zf.w, ef1.w, acc[i][1]);
      }
    }

    if (ks == 7) {                            // chunk exit: argmin update
#pragma unroll
      for (int i = 0; i < RPW; ++i) {
#pragma unroll
        for (int j = 0; j < 2; ++j) {
          int code = ch * CHUNK + lane + 64 * j;
          // d = (s - 2*dot) + se, rounded exactly like the reference
          float d = __fadd_rn(__fsub_rn(s_reg[i], __fmul_rn(2.0f, acc[i][j])),
                              se_reg[j]);
          if (d < bestd[i] || (d == bestd[i] && code < besti[i])) {
            bestd[i] = d; besti[i] = code;
          }
        }
      }
    }
    __syncthreads();                          // readers done; next stage safe
    b ^= 1;
  }

  // full-wave lexicographic (d, code) argmin reduce -> first-index tie-break
#pragma unroll
  for (int i = 0; i < RPW; ++i) {
    float bd = bestd[i];
    int   bi = besti[i];
#pragma unroll
    for (int off = 1; off < 64; off <<= 1) {
      float od = __shfl_xor(bd, off, 64);
      int   oi = __shfl_xor(bi, off, 64);
      if (od < bd || (od == bd && oi < bi)) { bd = od; bi = oi; }
    }
    if (lane == 0) best_l[wv * RPW + i] = bi;
  }
  __syncthreads();

  // epilogue: out0 = fl(z + fl(cb[idx]-z)), out1 = cb[idx]   (32 rows/block)
  const int r0 = blockIdx.x * RPB;
  const float4* zg = (const float4*)z;
  float4* out0 = (float4*)out;
  float4* out1 = (float4*)(out + (size_t)M_ROWS * DD);
#pragma unroll
  for (int it = 0; it < (RPB * 64) / 256; ++it) {
    int u = it * 256 + tid;
    int row = u >> 6, c4 = u & 63;
    size_t gidx = (size_t)(r0 + row) * 64 + c4;
    float4 zv = zg[gidx];
    float4 cv = cg[(size_t)best_l[row] * 64 + c4];
    float4 o0;
    o0.x = __fadd_rn(zv.x, __fsub_rn(cv.x, zv.x));
    o0.y = __fadd_rn(zv.y, __fsub_rn(cv.y, zv.y));
    o0.z = __fadd_rn(zv.z, __fsub_rn(cv.z, zv.z));
    o0.w = __fadd_rn(zv.w, __fsub_rn(cv.w, zv.w));
    out0[gidx] = o0;
    out1[gidx] = cv;
  }
}

extern "C" void kernel_launch(void* const* d_in, const int* in_sizes, int n_in,
                              void* d_out, int out_size, void* d_ws, size_t ws_size,
                              hipStream_t stream) {
  const float* z  = (const float*)d_in[0];   // [65536, 256]
  const float* cb = (const float*)d_in[1];   // [512, 256]
  float* out = (float*)d_out;                // 2 x [65536, 256] concat
  float* s  = (float*)d_ws;                  // ||z||^2 per row
  float* se = s + M_ROWS;                    // ||e||^2 per code

  sumsq_kernel<<<M_ROWS / 256, 256, 0, stream>>>(z, s, M_ROWS);
  sumsq_kernel<<<KC / 256, 256, 0, stream>>>(cb, se, KC);
  vq_kernel<<<M_ROWS / RPB, 256, 0, stream>>>(z, cb, s, se, out);
}